// Round 6
// baseline (673.816 us; speedup 1.0000x reference)
//
#include <hip/hip_runtime.h>
#include <hip/hip_bf16.h>
#include <math.h>

typedef __hip_bfloat16 bf16;
typedef unsigned int u32;
typedef __attribute__((ext_vector_type(8))) short bf16x8;
typedef __attribute__((ext_vector_type(4))) float f32x4;

#define BATCH 2
#define SEQ 1024
#define DM 1024
#define DI 2048
#define NST 16
#define DTR 64
#define XDN 96          // dt_rank + 2*N = 64+32
#define XDP_LD 128      // padded x_dbl row
#define T_TOK 2048      // BATCH*SEQ
#define N2 4096         // 2*DI
#define NCHUNK 16
#define CLEN 64
#define SCAN_BLOCKS 512 // (DI/256)*BATCH*2*NCHUNK

static __device__ __forceinline__ float b2f(bf16 v) { return __bfloat162float(v); }
static __device__ __forceinline__ float bits2f(unsigned short u) {
    return __uint_as_float(((unsigned)u) << 16);
}

// ---- async global->LDS, 16 bytes per lane; LDS dest must be wave-uniform base ----
static __device__ __forceinline__ void gload_lds16(const void* g, void* l) {
    __builtin_amdgcn_global_load_lds((__attribute__((address_space(1))) u32*)(size_t)g,
                                     (__attribute__((address_space(3))) u32*)l, 16, 0, 0);
}

// ---- 32x32 LDS tile transpose helper: in f32 [K][N] -> out bf16 [N][K] ----
static __device__ void tileT(const float* __restrict__ in, bf16* __restrict__ out,
                             int K, int N, int t, float (*tb)[33]) {
    int nt = N >> 5;
    int bx = (t % nt) << 5, by = (t / nt) << 5;
    int tx = threadIdx.x & 31, r0 = threadIdx.x >> 5;
#pragma unroll
    for (int r = r0; r < 32; r += 8)
        tb[r][tx] = in[(size_t)(by + r) * N + bx + tx];
    __syncthreads();
#pragma unroll
    for (int r = r0; r < 32; r += 8)
        out[(size_t)(bx + r) * K + by + tx] = __float2bfloat16(tb[tx][r]);
}

#define LN_BLKS   T_TOK                       // 2048
#define INW_T     ((N2 / 32) * (DM / 32))     // 4096
#define OUTW_T    ((DM / 32) * (DI / 32))     // 2048
#define MRGW_T    ((DI / 32) * (N2 / 32))     // 8192
#define SMALL_BLK ((2 * XDP_LD * DI + 2 * DI * DTR) / 256)  // 3072

// ---------------- prep_mega: LN + all weight preps + barrier init ----------------
__global__ __launch_bounds__(256) void prep_mega(const float* __restrict__ x,
                                                 const float* __restrict__ gamma,
                                                 const float* __restrict__ beta,
                                                 bf16* __restrict__ H,
                                                 const float* __restrict__ in_w, bf16* __restrict__ in_wT,
                                                 const float* __restrict__ out_w, bf16* __restrict__ out_wT,
                                                 const float* __restrict__ merge_w, bf16* __restrict__ merge_wT,
                                                 const float* __restrict__ xpf, const float* __restrict__ xpb,
                                                 bf16* __restrict__ XPF, bf16* __restrict__ XPB,
                                                 const float* __restrict__ dtwf, const float* __restrict__ dtwb,
                                                 bf16* __restrict__ dtwT,
                                                 u32* __restrict__ bar) {
    __shared__ float tbuf[32][33];
    __shared__ float red[8];
    int bid = blockIdx.x;
    int tid = threadIdx.x;
    if (bid == 0 && tid < 2) bar[tid] = 0;   // zero grid-barrier counters

    if (bid < LN_BLKS) {
        // ---- LayerNorm, one token per block ----
        int t = bid;
        float xv[4];
        float s = 0.f, s2 = 0.f;
#pragma unroll
        for (int k = 0; k < 4; ++k) {
            float v = x[(size_t)t * DM + k * 256 + tid];
            xv[k] = v; s += v; s2 += v * v;
        }
#pragma unroll
        for (int off = 32; off; off >>= 1) {
            s  += __shfl_down(s, off);
            s2 += __shfl_down(s2, off);
        }
        int wid = tid >> 6, lane = tid & 63;
        if (!lane) { red[wid] = s; red[4 + wid] = s2; }
        __syncthreads();
        if (tid == 0) {
            float S = red[0] + red[1] + red[2] + red[3];
            float S2 = red[4] + red[5] + red[6] + red[7];
            float mu = S * (1.f / DM);
            float var = S2 * (1.f / DM) - mu * mu;
            red[0] = mu;
            red[1] = rsqrtf(var + 1e-5f);
        }
        __syncthreads();
        float mu = red[0], rs = red[1];
#pragma unroll
        for (int k = 0; k < 4; ++k) {
            int i = k * 256 + tid;
            H[(size_t)t * DM + i] = __float2bfloat16((xv[k] - mu) * rs * gamma[i] + beta[i]);
        }
        return;
    }
    bid -= LN_BLKS;
    if (bid < INW_T)  { tileT(in_w, in_wT, DM, N2, bid, tbuf); return; }
    bid -= INW_T;
    if (bid < OUTW_T) { tileT(out_w, out_wT, DI, DM, bid, tbuf); return; }
    bid -= OUTW_T;
    if (bid < MRGW_T) { tileT(merge_w, merge_wT, N2, DI, bid, tbuf); return; }
    bid -= MRGW_T;
    // small: xproj pad-transpose + dt_w transpose
    int idx = bid * 256 + tid;
    if (idx < 2 * XDP_LD * DI) {
        int dir = idx >= XDP_LD * DI;
        int i = idx - dir * (XDP_LD * DI);
        int n = i >> 11;
        int k = i & (DI - 1);
        float v = (n < XDN) ? (dir ? xpb : xpf)[k * XDN + n] : 0.f;
        (dir ? XPB : XPF)[i] = __float2bfloat16(v);
    } else {
        int j = idx - 2 * XDP_LD * DI;     // over 2*2048*64
        int dir = j >= DI * DTR;
        int e = j - dir * (DI * DTR);
        int n = e >> 6;
        int k = e & 63;
        dtwT[(size_t)dir * DI * DTR + n * DTR + k] =
            __float2bfloat16((dir ? dtwb : dtwf)[(size_t)k * DI + n]);
    }
}

// ---------------- MFMA GEMM: C(MxN) = A(MxK,bf16,row-major) * BT(NxK,bf16)^T ----------------
// 128x128 tile, BK=64, 4 waves each 64x64 (4x4 of 16x16x32 MFMA); split-K over gridDim.z
// EPI 0: bf16 store to Cb
// EPI 1: outf = resid + acc (f32)
// EPI 2: f32 store to outf
// EPI 3: bf16 partial store to Pb + blockIdx.z*M*N
// EPI 4: dt: Cb = bf16(softplus(acc + bias[col])), bias = row<T_TOK ? bias1 : bias2
template <int EPI>
__global__ __launch_bounds__(256) void mfma_gemm(const bf16* __restrict__ A,
                                                 const bf16* __restrict__ BT,
                                                 const bf16* __restrict__ BT2, int bysplit,
                                                 bf16* __restrict__ Cb,
                                                 const float* __restrict__ resid,
                                                 float* __restrict__ outf,
                                                 bf16* __restrict__ Pb,
                                                 const float* __restrict__ bias1,
                                                 const float* __restrict__ bias2,
                                                 int M, int N, int K) {
    __shared__ bf16 As[8192];   // [kg 0..7][m 0..127][8]
    __shared__ bf16 Bs[8192];   // [kg 0..7][n 0..127][8]
    int tid = threadIdx.x;
    int wave = tid >> 6, lane = tid & 63;
    int q = lane >> 4, ln16 = lane & 15;
    int bm = blockIdx.y * 128, bn = blockIdx.x * 128;
    int wm = (wave >> 1) * 64, wn = (wave & 1) * 64;
    const bf16* Bt = ((int)blockIdx.y < bysplit) ? BT : BT2;

    int ks = K / gridDim.z;
    int kb = blockIdx.z * ks;

    f32x4 zf; zf[0] = zf[1] = zf[2] = zf[3] = 0.f;
    f32x4 acc[4][4];
#pragma unroll
    for (int i = 0; i < 4; ++i)
#pragma unroll
        for (int j = 0; j < 4; ++j) acc[i][j] = zf;

    for (int k0 = kb; k0 < kb + ks; k0 += 64) {
#pragma unroll
        for (int i = 0; i < 4; ++i) {
            int s = wave * 256 + i * 64 + lane;   // slot 0..1023
            int kg = s >> 7, m = s & 127;
            gload_lds16(&A[(size_t)(bm + m) * K + k0 + kg * 8], &As[(wave * 256 + i * 64) * 8]);
            gload_lds16(&Bt[(size_t)(bn + m) * K + k0 + kg * 8], &Bs[(wave * 256 + i * 64) * 8]);
        }
        __syncthreads();
#pragma unroll
        for (int kk = 0; kk < 2; ++kk) {
            bf16x8 af[4], bfr[4];
#pragma unroll
            for (int i = 0; i < 4; ++i) {
                af[i]  = *(const bf16x8*)&As[(((kk * 4 + q) * 128) + (wm + i * 16 + ln16)) * 8];
                bfr[i] = *(const bf16x8*)&Bs[(((kk * 4 + q) * 128) + (wn + i * 16 + ln16)) * 8];
            }
#pragma unroll
            for (int i = 0; i < 4; ++i)
#pragma unroll
                for (int j = 0; j < 4; ++j)
                    acc[i][j] = __builtin_amdgcn_mfma_f32_16x16x32_bf16(af[i], bfr[j], acc[i][j], 0, 0, 0);
        }
        __syncthreads();
    }

    size_t pbase = (size_t)blockIdx.z * M * N;
#pragma unroll
    for (int i = 0; i < 4; ++i)
#pragma unroll
        for (int r = 0; r < 4; ++r) {
            int row = bm + wm + i * 16 + q * 4 + r;
            const float* bias = (EPI == 4) ? ((row < T_TOK) ? bias1 : bias2) : nullptr;
#pragma unroll
            for (int j = 0; j < 4; ++j) {
                int col = bn + wn + j * 16 + ln16;
                size_t idx = (size_t)row * N + col;
                float v = acc[i][j][r];
                if (EPI == 0)      Cb[idx] = __float2bfloat16(v);
                else if (EPI == 1) outf[idx] = resid[idx] + v;
                else if (EPI == 2) outf[idx] = v;
                else if (EPI == 3) Pb[pbase + idx] = __float2bfloat16(v);
                else {
                    float t = v + bias[col];
                    float sp = (t > 20.f) ? t : log1pf(__expf(t));
                    Cb[idx] = __float2bfloat16(sp);
                }
            }
        }
}

// ---------------- split-K reduce kernels (bf16 partials) ----------------
__global__ __launch_bounds__(256) void reduce_gate(const bf16* __restrict__ P, int ns, size_t MN,
                                                   const bf16* __restrict__ XZ, bf16* __restrict__ YM) {
    size_t i = ((size_t)blockIdx.x * 256 + threadIdx.x) * 4;  // over T_TOK*DI
    float s[4] = {0.f, 0.f, 0.f, 0.f};
    for (int k = 0; k < ns; ++k) {
        ushort4 p = *reinterpret_cast<const ushort4*>(&P[(size_t)k * MN + i]);
        s[0] += bits2f(p.x); s[1] += bits2f(p.y); s[2] += bits2f(p.z); s[3] += bits2f(p.w);
    }
    int t = (int)(i >> 11), c = (int)(i & (DI - 1));
    const bf16* zp = &XZ[(size_t)t * N2 + DI + c];
    bf16 r[4];
#pragma unroll
    for (int j = 0; j < 4; ++j) {
        float z = b2f(zp[j]);
        r[j] = __float2bfloat16(s[j] * (z / (1.f + __expf(-z))));
    }
    *reinterpret_cast<ushort4*>(&YM[i]) = *reinterpret_cast<ushort4*>(r);
}

__global__ __launch_bounds__(256) void reduce_out(const bf16* __restrict__ P, int ns, size_t MN,
                                                  const float* __restrict__ x, float* __restrict__ out) {
    size_t i = ((size_t)blockIdx.x * 256 + threadIdx.x) * 4;  // over T_TOK*DM
    float s[4] = {0.f, 0.f, 0.f, 0.f};
    for (int k = 0; k < ns; ++k) {
        ushort4 p = *reinterpret_cast<const ushort4*>(&P[(size_t)k * MN + i]);
        s[0] += bits2f(p.x); s[1] += bits2f(p.y); s[2] += bits2f(p.z); s[3] += bits2f(p.w);
    }
    float4 xv = *reinterpret_cast<const float4*>(&x[i]);
    float4 o = {s[0] + xv.x, s[1] + xv.y, s[2] + xv.z, s[3] + xv.w};
    *reinterpret_cast<float4*>(&out[i]) = o;
}

__global__ __launch_bounds__(256) void reduce_xdbl(const bf16* __restrict__ P, int ns, size_t MN,
                                                   float* __restrict__ XDP, bf16* __restrict__ XDdt) {
    size_t i = ((size_t)blockIdx.x * 256 + threadIdx.x) * 4;  // over 2*T_TOK*128
    float s[4] = {0.f, 0.f, 0.f, 0.f};
    for (int k = 0; k < ns; ++k) {
        ushort4 p = *reinterpret_cast<const ushort4*>(&P[(size_t)k * MN + i]);
        s[0] += bits2f(p.x); s[1] += bits2f(p.y); s[2] += bits2f(p.z); s[3] += bits2f(p.w);
    }
    float4 o = {s[0], s[1], s[2], s[3]};
    *reinterpret_cast<float4*>(&XDP[i]) = o;
    int col = (int)(i & (XDP_LD - 1));
    if (col < DTR) {
        size_t row = i >> 7;
        bf16 r[4];
#pragma unroll
        for (int j = 0; j < 4; ++j) r[j] = __float2bfloat16(s[j]);
        *reinterpret_cast<ushort4*>(&XDdt[row * DTR + col]) = *reinterpret_cast<ushort4*>(r);
    }
}

// ---------------- dt GEMM fallback (vector, K=64, reads XDP fp32) ----------------
__global__ __launch_bounds__(256) void gemm_dt(const float* __restrict__ A,   // lda=128
                                               const float* __restrict__ Bw,  // 64 x 2048 f32
                                               const float* __restrict__ bias,
                                               bf16* __restrict__ Cb, int M, int N) {
    __shared__ float As[16][68];
    __shared__ float Bs[16][68];
    int tid = threadIdx.x;
    int bm = blockIdx.y * 64, bn = blockIdx.x * 64;
    int tx = tid & 15, ty = tid >> 4;
    float acc[4][4];
#pragma unroll
    for (int i = 0; i < 4; ++i)
#pragma unroll
        for (int j = 0; j < 4; ++j) acc[i][j] = 0.f;
    int arow = tid >> 2, acg = (tid & 3) * 4;
    int brow = tid >> 4, bcol = (tid & 15) * 4;
    for (int k0 = 0; k0 < DTR; k0 += 16) {
        float4 av = *reinterpret_cast<const float4*>(&A[(size_t)(bm + arow) * XDP_LD + k0 + acg]);
        As[acg + 0][arow] = av.x; As[acg + 1][arow] = av.y;
        As[acg + 2][arow] = av.z; As[acg + 3][arow] = av.w;
        float4 bv = *reinterpret_cast<const float4*>(&Bw[(size_t)(k0 + brow) * N + bn + bcol]);
        Bs[brow][bcol + 0] = bv.x; Bs[brow][bcol + 1] = bv.y;
        Bs[brow][bcol + 2] = bv.z; Bs[brow][bcol + 3] = bv.w;
        __syncthreads();
#pragma unroll
        for (int kk = 0; kk < 16; ++kk) {
            float4 a = *reinterpret_cast<const float4*>(&As[kk][ty * 4]);
            float4 b = *reinterpret_cast<const float4*>(&Bs[kk][tx * 4]);
            acc[0][0] += a.x * b.x; acc[0][1] += a.x * b.y; acc[0][2] += a.x * b.z; acc[0][3] += a.x * b.w;
            acc[1][0] += a.y * b.x; acc[1][1] += a.y * b.y; acc[1][2] += a.y * b.z; acc[1][3] += a.y * b.w;
            acc[2][0] += a.z * b.x; acc[2][1] += a.z * b.y; acc[2][2] += a.z * b.z; acc[2][3] += a.z * b.w;
            acc[3][0] += a.w * b.x; acc[3][1] += a.w * b.y; acc[3][2] += a.w * b.z; acc[3][3] += a.w * b.w;
        }
        __syncthreads();
    }
    int row0 = bm + ty * 4, col0 = bn + tx * 4;
#pragma unroll
    for (int i = 0; i < 4; ++i)
#pragma unroll
        for (int j = 0; j < 4; ++j) {
            float v = acc[i][j] + bias[col0 + j];
            float sp = (v > 20.f) ? v : log1pf(__expf(v));
            Cb[(size_t)(row0 + i) * N + col0 + j] = __float2bfloat16(sp);
        }
}

// ---------------- depthwise causal conv (fwd) + anti-causal (bwd) + SiLU ----------------
__global__ __launch_bounds__(256) void conv_kernel(const bf16* __restrict__ XZ,
                                                   const float* __restrict__ wf, const float* __restrict__ bf_,
                                                   const float* __restrict__ wb, const float* __restrict__ bb_,
                                                   bf16* __restrict__ XCF, bf16* __restrict__ XCB) {
    int idx = blockIdx.x * 256 + threadIdx.x;   // over T_TOK*DI
    int c = idx & (DI - 1);
    int g = idx >> 11;
    int l = g & (SEQ - 1);
    int b = g >> 10;
    float sf = bf_[c];
    float sb = bb_[c];
#pragma unroll
    for (int j = 0; j < 4; ++j) {
        int lf = l - 3 + j;
        if (lf >= 0) sf += wf[c * 4 + j] * b2f(XZ[((size_t)(b * SEQ + lf)) * N2 + c]);
        int lb = l + 3 - j;
        if (lb < SEQ) sb += wb[c * 4 + j] * b2f(XZ[((size_t)(b * SEQ + lb)) * N2 + c]);
    }
    XCF[idx] = __float2bfloat16(sf / (1.f + __expf(-sf)));
    XCB[idx] = __float2bfloat16(sb / (1.f + __expf(-sb)));
}

// ---------------- fused chunked selective scan (A + B + C, manual grid barrier) ----------------
static __device__ __forceinline__ void grid_barrier(u32* cnt, u32 target) {
    __syncthreads();
    if (threadIdx.x == 0) {
        __threadfence();                       // release: HLOC/SUMDT writes visible device-wide
        atomicAdd(cnt, 1u);
        while (__hip_atomic_load(cnt, __ATOMIC_ACQUIRE, __HIP_MEMORY_SCOPE_AGENT) < target)
            __builtin_amdgcn_s_sleep(8);
    }
    __syncthreads();
    __threadfence();                           // acquire on all threads
}

__global__ __launch_bounds__(256, 2) void scan_fused(const bf16* __restrict__ DTF_, const bf16* __restrict__ DTB_,
                                                     const bf16* __restrict__ XCF_, const bf16* __restrict__ XCB_,
                                                     const float* __restrict__ XDP,
                                                     const float* __restrict__ Af, const float* __restrict__ Ab,
                                                     const float* __restrict__ Df, const float* __restrict__ Db,
                                                     float* HLOC, float* SUMDT,
                                                     u32* bar, bf16* __restrict__ YCAT) {
    int tid = threadIdx.x;
    int c = blockIdx.x * 256 + tid;
    int b = blockIdx.y;
    int dir = blockIdx.z >> 4, chunk = blockIdx.z & 15;
    const bf16* DT = dir ? DTB_ : DTF_;
    const bf16* XC = dir ? XCB_ : XCF_;
    const float* Al = dir ? Ab : Af;
    float A[NST];
#pragma unroll
    for (int n = 0; n < NST; ++n) A[n] = -__expf(Al[c * NST + n]);
    size_t base = ((((size_t)dir * BATCH + b) * NCHUNK + chunk) * DI + c);

    // ---- phase A: chunk-local scan from h=0 ----
    {
        float h[NST];
#pragma unroll
        for (int n = 0; n < NST; ++n) h[n] = 0.f;
        float sumdt = 0.f;
        for (int it = 0; it < CLEN; ++it) {
            int sit = chunk * CLEN + it;
            int l = dir ? (SEQ - 1 - sit) : sit;
            size_t g = (size_t)b * SEQ + l;
            float dt = b2f(DT[g * DI + c]);
            float xc = b2f(XC[g * DI + c]);
            float dtxc = dt * xc;
            const float* bs = &XDP[((size_t)dir * T_TOK + g) * XDP_LD + DTR];
            sumdt += dt;
#pragma unroll
            for (int n = 0; n < NST; ++n)
                h[n] = __expf(dt * A[n]) * h[n] + dtxc * bs[n];
        }
#pragma unroll
        for (int n = 0; n < NST; ++n) HLOC[base * NST + n] = h[n];
        SUMDT[base] = sumdt;
    }
    grid_barrier(bar + 0, SCAN_BLOCKS);

    // ---- phase B: sequential combine over chunks (one (dir,b,c,n) per thread) ----
    {
        int idx = (((int)blockIdx.z * BATCH + (int)blockIdx.y) * (DI / 256) + (int)blockIdx.x) * 256 + tid;
        int n2 = idx & 15;
        int c2 = (idx >> 4) & (DI - 1);
        int b2 = (idx >> 15) & 1;
        int dir2 = idx >> 16;
        float A2 = -__expf((dir2 ? Ab : Af)[c2 * NST + n2]);
        float hh = 0.f;
        for (int k = 0; k < NCHUNK; ++k) {
            size_t base2 = ((((size_t)dir2 * BATCH + b2) * NCHUNK + k) * DI + c2);
            float P = __expf(A2 * SUMDT[base2]);
            float hl = HLOC[base2 * NST + n2];
            HLOC[base2 * NST + n2] = hh;
            hh = P * hh + hl;
        }
    }
    grid_barrier(bar + 1, SCAN_BLOCKS);

    // ---- phase C: rescan from exact carry-in, emit y ----
    {
        float h[NST];
#pragma unroll
        for (int n = 0; n < NST; ++n) h[n] = HLOC[base * NST + n];
        float Dv = (dir ? Db : Df)[c];
        for (int it = 0; it < CLEN; ++it) {
            int sit = chunk * CLEN + it;
            int l = dir ? (SEQ - 1 - sit) : sit;
            size_t g = (size_t)b * SEQ + l;
            float dt = b2f(DT[g * DI + c]);
            float xc = b2f(XC[g * DI + c]);
            float dtxc = dt * xc;
            const float* bs = &XDP[((size_t)dir * T_TOK + g) * XDP_LD + DTR];
            float y = 0.f;
#pragma unroll
            for (int n = 0; n < NST; ++n) {
                h[n] = __expf(dt * A[n]) * h[n] + dtxc * bs[n];
                y += h[n] * bs[NST + n];
            }
            YCAT[g * N2 + dir * DI + c] = __float2bfloat16(y + xc * Dv);
        }
    }
}

// ---------------- gating fallback: YM *= silu(z) ----------------
__global__ __launch_bounds__(256) void gate_kernel(bf16* __restrict__ YM, const bf16* __restrict__ XZ) {
    int idx = blockIdx.x * 256 + threadIdx.x;  // over T_TOK*DI
    int t = idx >> 11;
    int c = idx & (DI - 1);
    float z = b2f(XZ[(size_t)t * N2 + DI + c]);
    float y = b2f(YM[idx]);
    YM[idx] = __float2bfloat16(y * (z / (1.f + __expf(-z))));
}

extern "C" void kernel_launch(void* const* d_in, const int* in_sizes, int n_in,
                              void* d_out, int out_size, void* d_ws, size_t ws_size,
                              hipStream_t stream) {
    const float* x       = (const float*)d_in[0];
    const float* gamma   = (const float*)d_in[1];
    const float* beta    = (const float*)d_in[2];
    const float* in_w    = (const float*)d_in[3];
    const float* conv_w  = (const float*)d_in[4];
    const float* conv_b  = (const float*)d_in[5];
    const float* xproj_w = (const float*)d_in[6];
    const float* dt_w    = (const float*)d_in[7];
    const float* dt_b    = (const float*)d_in[8];
    const float* A_log   = (const float*)d_in[9];
    const float* D_skip  = (const float*)d_in[10];
    const float* conv_w_b  = (const float*)d_in[11];
    const float* conv_b_b  = (const float*)d_in[12];
    const float* xproj_w_b = (const float*)d_in[13];
    const float* dt_w_b    = (const float*)d_in[14];
    const float* dt_b_b    = (const float*)d_in[15];
    const float* A_log_b   = (const float*)d_in[16];
    const float* D_skip_b  = (const float*)d_in[17];
    const float* merge_w   = (const float*)d_in[18];
    const float* out_w     = (const float*)d_in[19];
    float* out = (float*)d_out;

    // ---- base workspace layout ----
    char* w = (char*)d_ws;
    size_t off = 0;
    bf16* H       = (bf16*)(w + off); off += (size_t)T_TOK * DM * 2;          //  4.19 MB
    bf16* XZ      = (bf16*)(w + off); off += (size_t)T_TOK * N2 * 2;          // 16.78 MB
    bf16* XCF     = (bf16*)(w + off); off += (size_t)T_TOK * DI * 2;          //  8.39 MB
    bf16* XCB     = (bf16*)(w + off); off += (size_t)T_TOK * DI * 2;          //  8.39 MB
    bf16* XPF     = (bf16*)(w + off); off += (size_t)XDP_LD * DI * 2;         //  0.52 MB
    bf16* XPB     = (bf16*)(w + off); off += (size_t)XDP_LD * DI * 2;         //  0.52 MB
    float* XDP    = (float*)(w + off); off += (size_t)2 * T_TOK * XDP_LD * 4; //  2.10 MB
    bf16* DTF     = (bf16*)(w + off); off += (size_t)T_TOK * DI * 2;          //  8.39 MB
    bf16* DTB     = (bf16*)(w + off); off += (size_t)T_TOK * DI * 2;          //  8.39 MB (contig after DTF)
    bf16* YCAT    = (bf16*)(w + off); off += (size_t)T_TOK * N2 * 2;          // 16.78 MB
    bf16* in_wT   = (bf16*)(w + off); off += (size_t)N2 * DM * 2;             //  8.39 MB
    bf16* out_wT  = (bf16*)(w + off); off += (size_t)DM * DI * 2;             //  4.19 MB
    bf16* merge_wT= (bf16*)(w + off); off += (size_t)DI * N2 * 2;             // 16.78 MB
    bf16* dtwT    = (bf16*)(w + off); off += (size_t)2 * DI * DTR * 2;        //  0.52 MB
    bf16* XDdt    = (bf16*)(w + off); off += (size_t)2 * T_TOK * DTR * 2;     //  0.52 MB
    u32*  bar     = (u32*)(w + off);  off += 256;                             //  barrier counters (dedicated)
    // PART region: time-shared {xdbl partials | HLOC+SUMDT | merge partials | out partials}
    char* PART = w + off;
    size_t avail = (ws_size > off) ? ws_size - off : 0;

    float* HLOC  = (float*)PART;                                              // 8.39 MB
    float* SUMDT = (float*)(PART + (size_t)2 * BATCH * NCHUNK * DI * NST * 4);// +0.52 MB
    bf16* Pb     = (bf16*)PART;                                               // split-K bf16 partials
    bf16* YM     = DTF;    // alias: DTF dead after scan_fused

    size_t MNm = (size_t)T_TOK * DI;          // merge partial elems
    size_t MNo = (size_t)T_TOK * DM;          // out partial elems
    size_t MNx = (size_t)2 * T_TOK * XDP_LD;  // xdbl partial elems
    int s_merge = (avail >= 4 * MNm * 2) ? 4 : (avail >= 2 * MNm * 2) ? 2 : 0;
    int s_out   = (avail >= 4 * MNo * 2) ? 4 : (avail >= 2 * MNo * 2) ? 2 : 0;
    int s_xdbl  = (avail >= 16 * MNx * 2) ? 16 : (avail >= 8 * MNx * 2) ? 8 : (avail >= 4 * MNx * 2) ? 4 : 0;

    // 1. mega prep: LN + in_wT + out_wT + merge_wT + xproj/dtw + barrier init
    prep_mega<<<LN_BLKS + INW_T + OUTW_T + MRGW_T + SMALL_BLK, 256, 0, stream>>>(
        x, gamma, beta, H, in_w, in_wT, out_w, out_wT, merge_w, merge_wT,
        xproj_w, xproj_w_b, XPF, XPB, dt_w, dt_w_b, dtwT, bar);
    // 2. xz = H @ in_w  (M=2048, N=4096, K=1024) -> XZ bf16
    mfma_gemm<0><<<dim3(N2 / 128, T_TOK / 128), 256, 0, stream>>>(
        H, in_wT, in_wT, 1 << 30, XZ, nullptr, nullptr, nullptr, nullptr, nullptr, T_TOK, N2, DM);
    // 3. depthwise conv + silu, both dirs
    conv_kernel<<<(T_TOK * DI) / 256, 256, 0, stream>>>(XZ, conv_w, conv_b, conv_w_b, conv_b_b, XCF, XCB);
    // 4. x_dbl (padded): XDP = [XCF;XCB] @ xproj (M=4096, N=128, K=2048), B per dir
    if (s_xdbl) {
        mfma_gemm<3><<<dim3(1, (2 * T_TOK) / 128, s_xdbl), 256, 0, stream>>>(
            XCF, XPF, XPB, (T_TOK / 128), nullptr, nullptr, nullptr, Pb, nullptr, nullptr,
            2 * T_TOK, XDP_LD, DI);
        reduce_xdbl<<<(int)(MNx / 4 / 256), 256, 0, stream>>>(Pb, s_xdbl, MNx, XDP, XDdt);
        // 5. dt = softplus(XDdt @ dt_w + dt_b) via MFMA (M=4096 both dirs, N=2048, K=64)
        mfma_gemm<4><<<dim3(DI / 128, (2 * T_TOK) / 128), 256, 0, stream>>>(
            XDdt, dtwT, dtwT + (size_t)DI * DTR, (T_TOK / 128), DTF, nullptr, nullptr, nullptr,
            dt_b, dt_b_b, 2 * T_TOK, DI, DTR);
    } else {
        mfma_gemm<2><<<dim3(1, (2 * T_TOK) / 128), 256, 0, stream>>>(
            XCF, XPF, XPB, (T_TOK / 128), nullptr, nullptr, XDP, nullptr, nullptr, nullptr,
            2 * T_TOK, XDP_LD, DI);
        gemm_dt<<<dim3(DI / 64, T_TOK / 64), 256, 0, stream>>>(XDP, dt_w, dt_b, DTF, T_TOK, DI);
        gemm_dt<<<dim3(DI / 64, T_TOK / 64), 256, 0, stream>>>(XDP + (size_t)T_TOK * XDP_LD, dt_w_b, dt_b_b, DTB, T_TOK, DI);
    }
    // 6. fused chunked scan (A + combine + C) -> YCAT
    scan_fused<<<dim3(DI / 256, BATCH, 2 * NCHUNK), 256, 0, stream>>>(
        DTF, DTB, XCF, XCB, XDP, A_log, A_log_b, D_skip, D_skip_b, HLOC, SUMDT, bar, YCAT);
    // 7. YM = silu(z) * (YCAT @ merge_w) (M=2048, N=2048, K=4096)
    if (s_merge) {
        mfma_gemm<3><<<dim3(DI / 128, T_TOK / 128, s_merge), 256, 0, stream>>>(
            YCAT, merge_wT, merge_wT, 1 << 30, nullptr, nullptr, nullptr, Pb, nullptr, nullptr,
            T_TOK, DI, N2);
        reduce_gate<<<(int)(MNm / 4 / 256), 256, 0, stream>>>(Pb, s_merge, MNm, XZ, YM);
    } else {
        mfma_gemm<0><<<dim3(DI / 128, T_TOK / 128), 256, 0, stream>>>(
            YCAT, merge_wT, merge_wT, 1 << 30, YM, nullptr, nullptr, nullptr, nullptr, nullptr,
            T_TOK, DI, N2);
        gate_kernel<<<(T_TOK * DI) / 256, 256, 0, stream>>>(YM, XZ);
    }
    // 8. out = x + YM @ out_w (M=2048, N=1024, K=2048), f32
    if (s_out) {
        mfma_gemm<3><<<dim3(DM / 128, T_TOK / 128, s_out), 256, 0, stream>>>(
            YM, out_wT, out_wT, 1 << 30, nullptr, nullptr, nullptr, Pb, nullptr, nullptr,
            T_TOK, DM, DI);
        reduce_out<<<(int)(MNo / 4 / 256), 256, 0, stream>>>(Pb, s_out, MNo, x, out);
    } else {
        mfma_gemm<1><<<dim3(DM / 128, T_TOK / 128), 256, 0, stream>>>(
            YM, out_wT, out_wT, 1 << 30, nullptr, x, out, nullptr, nullptr, nullptr,
            T_TOK, DM, DI);
    }
}

// Round 7
// 484.577 us; speedup vs baseline: 1.3905x; 1.3905x over previous
//
#include <hip/hip_runtime.h>
#include <hip/hip_bf16.h>
#include <math.h>

typedef __hip_bfloat16 bf16;
typedef unsigned int u32;
typedef __attribute__((ext_vector_type(8))) short bf16x8;
typedef __attribute__((ext_vector_type(4))) float f32x4;

#define BATCH 2
#define SEQ 1024
#define DM 1024
#define DI 2048
#define NST 16
#define DTR 64
#define XDN 96          // dt_rank + 2*N = 64+32
#define XDP_LD 128      // padded x_dbl row
#define T_TOK 2048      // BATCH*SEQ
#define N2 4096         // 2*DI
#define NCHUNK 16
#define CLEN 64

static __device__ __forceinline__ float b2f(bf16 v) { return __bfloat162float(v); }
static __device__ __forceinline__ float bits2f(unsigned short u) {
    return __uint_as_float(((unsigned)u) << 16);
}

// ---- async global->LDS, 16 bytes per lane; LDS dest must be wave-uniform base ----
static __device__ __forceinline__ void gload_lds16(const void* g, void* l) {
    __builtin_amdgcn_global_load_lds((__attribute__((address_space(1))) u32*)(size_t)g,
                                     (__attribute__((address_space(3))) u32*)l, 16, 0, 0);
}

// ---- 32x32 LDS tile transpose helper: in f32 [K][N] -> out bf16 [N][K] ----
static __device__ void tileT(const float* __restrict__ in, bf16* __restrict__ out,
                             int K, int N, int t, float (*tb)[33]) {
    int nt = N >> 5;
    int bx = (t % nt) << 5, by = (t / nt) << 5;
    int tx = threadIdx.x & 31, r0 = threadIdx.x >> 5;
#pragma unroll
    for (int r = r0; r < 32; r += 8)
        tb[r][tx] = in[(size_t)(by + r) * N + bx + tx];
    __syncthreads();
#pragma unroll
    for (int r = r0; r < 32; r += 8)
        out[(size_t)(bx + r) * K + by + tx] = __float2bfloat16(tb[tx][r]);
}

#define LN_BLKS   T_TOK                       // 2048
#define INW_T     ((N2 / 32) * (DM / 32))     // 4096
#define OUTW_T    ((DM / 32) * (DI / 32))     // 2048
#define MRGW_T    ((DI / 32) * (N2 / 32))     // 8192
#define SMALL_BLK ((2 * XDP_LD * DI + 2 * DI * DTR) / 256)  // 3072

// ---------------- prep_mega: LN + all weight preps ----------------
__global__ __launch_bounds__(256) void prep_mega(const float* __restrict__ x,
                                                 const float* __restrict__ gamma,
                                                 const float* __restrict__ beta,
                                                 bf16* __restrict__ H,
                                                 const float* __restrict__ in_w, bf16* __restrict__ in_wT,
                                                 const float* __restrict__ out_w, bf16* __restrict__ out_wT,
                                                 const float* __restrict__ merge_w, bf16* __restrict__ merge_wT,
                                                 const float* __restrict__ xpf, const float* __restrict__ xpb,
                                                 bf16* __restrict__ XPF, bf16* __restrict__ XPB,
                                                 const float* __restrict__ dtwf, const float* __restrict__ dtwb,
                                                 bf16* __restrict__ dtwT) {
    __shared__ float tbuf[32][33];
    __shared__ float red[8];
    int bid = blockIdx.x;
    int tid = threadIdx.x;

    if (bid < LN_BLKS) {
        // ---- LayerNorm, one token per block ----
        int t = bid;
        float xv[4];
        float s = 0.f, s2 = 0.f;
#pragma unroll
        for (int k = 0; k < 4; ++k) {
            float v = x[(size_t)t * DM + k * 256 + tid];
            xv[k] = v; s += v; s2 += v * v;
        }
#pragma unroll
        for (int off = 32; off; off >>= 1) {
            s  += __shfl_down(s, off);
            s2 += __shfl_down(s2, off);
        }
        int wid = tid >> 6, lane = tid & 63;
        if (!lane) { red[wid] = s; red[4 + wid] = s2; }
        __syncthreads();
        if (tid == 0) {
            float S = red[0] + red[1] + red[2] + red[3];
            float S2 = red[4] + red[5] + red[6] + red[7];
            float mu = S * (1.f / DM);
            float var = S2 * (1.f / DM) - mu * mu;
            red[0] = mu;
            red[1] = rsqrtf(var + 1e-5f);
        }
        __syncthreads();
        float mu = red[0], rs = red[1];
#pragma unroll
        for (int k = 0; k < 4; ++k) {
            int i = k * 256 + tid;
            H[(size_t)t * DM + i] = __float2bfloat16((xv[k] - mu) * rs * gamma[i] + beta[i]);
        }
        return;
    }
    bid -= LN_BLKS;
    if (bid < INW_T)  { tileT(in_w, in_wT, DM, N2, bid, tbuf); return; }
    bid -= INW_T;
    if (bid < OUTW_T) { tileT(out_w, out_wT, DI, DM, bid, tbuf); return; }
    bid -= OUTW_T;
    if (bid < MRGW_T) { tileT(merge_w, merge_wT, N2, DI, bid, tbuf); return; }
    bid -= MRGW_T;
    // small: xproj pad-transpose + dt_w transpose
    int idx = bid * 256 + tid;
    if (idx < 2 * XDP_LD * DI) {
        int dir = idx >= XDP_LD * DI;
        int i = idx - dir * (XDP_LD * DI);
        int n = i >> 11;
        int k = i & (DI - 1);
        float v = (n < XDN) ? (dir ? xpb : xpf)[k * XDN + n] : 0.f;
        (dir ? XPB : XPF)[i] = __float2bfloat16(v);
    } else {
        int j = idx - 2 * XDP_LD * DI;     // over 2*2048*64
        int dir = j >= DI * DTR;
        int e = j - dir * (DI * DTR);
        int n = e >> 6;
        int k = e & 63;
        dtwT[(size_t)dir * DI * DTR + n * DTR + k] =
            __float2bfloat16((dir ? dtwb : dtwf)[(size_t)k * DI + n]);
    }
}

// ---------------- MFMA GEMM: C(MxN) = A(MxK,bf16,row-major) * BT(NxK,bf16)^T ----------------
// 128x128 tile, BK=64, 4 waves each 64x64 (4x4 of 16x16x32 MFMA); split-K over gridDim.z
// EPI 0: bf16 store to Cb
// EPI 1: outf = resid + acc (f32)
// EPI 2: f32 store to outf
// EPI 3: bf16 partial store to Pb + blockIdx.z*M*N
// EPI 4: dt: Cb = bf16(softplus(acc + bias[col])), bias = row<T_TOK ? bias1 : bias2
template <int EPI>
__global__ __launch_bounds__(256) void mfma_gemm(const bf16* __restrict__ A,
                                                 const bf16* __restrict__ BT,
                                                 const bf16* __restrict__ BT2, int bysplit,
                                                 bf16* __restrict__ Cb,
                                                 const float* __restrict__ resid,
                                                 float* __restrict__ outf,
                                                 bf16* __restrict__ Pb,
                                                 const float* __restrict__ bias1,
                                                 const float* __restrict__ bias2,
                                                 int M, int N, int K) {
    __shared__ bf16 As[8192];   // [kg 0..7][m 0..127][8]
    __shared__ bf16 Bs[8192];   // [kg 0..7][n 0..127][8]
    int tid = threadIdx.x;
    int wave = tid >> 6, lane = tid & 63;
    int q = lane >> 4, ln16 = lane & 15;
    int bm = blockIdx.y * 128, bn = blockIdx.x * 128;
    int wm = (wave >> 1) * 64, wn = (wave & 1) * 64;
    const bf16* Bt = ((int)blockIdx.y < bysplit) ? BT : BT2;

    int ks = K / gridDim.z;
    int kb = blockIdx.z * ks;

    f32x4 zf; zf[0] = zf[1] = zf[2] = zf[3] = 0.f;
    f32x4 acc[4][4];
#pragma unroll
    for (int i = 0; i < 4; ++i)
#pragma unroll
        for (int j = 0; j < 4; ++j) acc[i][j] = zf;

    for (int k0 = kb; k0 < kb + ks; k0 += 64) {
#pragma unroll
        for (int i = 0; i < 4; ++i) {
            int s = wave * 256 + i * 64 + lane;   // slot 0..1023
            int kg = s >> 7, m = s & 127;
            gload_lds16(&A[(size_t)(bm + m) * K + k0 + kg * 8], &As[(wave * 256 + i * 64) * 8]);
            gload_lds16(&Bt[(size_t)(bn + m) * K + k0 + kg * 8], &Bs[(wave * 256 + i * 64) * 8]);
        }
        __syncthreads();
#pragma unroll
        for (int kk = 0; kk < 2; ++kk) {
            bf16x8 af[4], bfr[4];
#pragma unroll
            for (int i = 0; i < 4; ++i) {
                af[i]  = *(const bf16x8*)&As[(((kk * 4 + q) * 128) + (wm + i * 16 + ln16)) * 8];
                bfr[i] = *(const bf16x8*)&Bs[(((kk * 4 + q) * 128) + (wn + i * 16 + ln16)) * 8];
            }
#pragma unroll
            for (int i = 0; i < 4; ++i)
#pragma unroll
                for (int j = 0; j < 4; ++j)
                    acc[i][j] = __builtin_amdgcn_mfma_f32_16x16x32_bf16(af[i], bfr[j], acc[i][j], 0, 0, 0);
        }
        __syncthreads();
    }

    size_t pbase = (size_t)blockIdx.z * M * N;
#pragma unroll
    for (int i = 0; i < 4; ++i)
#pragma unroll
        for (int r = 0; r < 4; ++r) {
            int row = bm + wm + i * 16 + q * 4 + r;
            const float* bias = (EPI == 4) ? ((row < T_TOK) ? bias1 : bias2) : nullptr;
#pragma unroll
            for (int j = 0; j < 4; ++j) {
                int col = bn + wn + j * 16 + ln16;
                size_t idx = (size_t)row * N + col;
                float v = acc[i][j][r];
                if (EPI == 0)      Cb[idx] = __float2bfloat16(v);
                else if (EPI == 1) outf[idx] = resid[idx] + v;
                else if (EPI == 2) outf[idx] = v;
                else if (EPI == 3) Pb[pbase + idx] = __float2bfloat16(v);
                else {
                    float t = v + bias[col];
                    float sp = (t > 20.f) ? t : log1pf(__expf(t));
                    Cb[idx] = __float2bfloat16(sp);
                }
            }
        }
}

// ---------------- split-K reduce kernels (bf16 partials) ----------------
__global__ __launch_bounds__(256) void reduce_gate(const bf16* __restrict__ P, int ns, size_t MN,
                                                   const bf16* __restrict__ XZ, bf16* __restrict__ YM) {
    size_t i = ((size_t)blockIdx.x * 256 + threadIdx.x) * 4;  // over T_TOK*DI
    float s[4] = {0.f, 0.f, 0.f, 0.f};
    for (int k = 0; k < ns; ++k) {
        ushort4 p = *reinterpret_cast<const ushort4*>(&P[(size_t)k * MN + i]);
        s[0] += bits2f(p.x); s[1] += bits2f(p.y); s[2] += bits2f(p.z); s[3] += bits2f(p.w);
    }
    int t = (int)(i >> 11), c = (int)(i & (DI - 1));
    const bf16* zp = &XZ[(size_t)t * N2 + DI + c];
    bf16 r[4];
#pragma unroll
    for (int j = 0; j < 4; ++j) {
        float z = b2f(zp[j]);
        r[j] = __float2bfloat16(s[j] * (z / (1.f + __expf(-z))));
    }
    *reinterpret_cast<ushort4*>(&YM[i]) = *reinterpret_cast<ushort4*>(r);
}

__global__ __launch_bounds__(256) void reduce_out(const bf16* __restrict__ P, int ns, size_t MN,
                                                  const float* __restrict__ x, float* __restrict__ out) {
    size_t i = ((size_t)blockIdx.x * 256 + threadIdx.x) * 4;  // over T_TOK*DM
    float s[4] = {0.f, 0.f, 0.f, 0.f};
    for (int k = 0; k < ns; ++k) {
        ushort4 p = *reinterpret_cast<const ushort4*>(&P[(size_t)k * MN + i]);
        s[0] += bits2f(p.x); s[1] += bits2f(p.y); s[2] += bits2f(p.z); s[3] += bits2f(p.w);
    }
    float4 xv = *reinterpret_cast<const float4*>(&x[i]);
    float4 o = {s[0] + xv.x, s[1] + xv.y, s[2] + xv.z, s[3] + xv.w};
    *reinterpret_cast<float4*>(&out[i]) = o;
}

__global__ __launch_bounds__(256) void reduce_xdbl(const bf16* __restrict__ P, int ns, size_t MN,
                                                   float* __restrict__ XDP, bf16* __restrict__ XDdt) {
    size_t i = ((size_t)blockIdx.x * 256 + threadIdx.x) * 4;  // over 2*T_TOK*128
    float s[4] = {0.f, 0.f, 0.f, 0.f};
    for (int k = 0; k < ns; ++k) {
        ushort4 p = *reinterpret_cast<const ushort4*>(&P[(size_t)k * MN + i]);
        s[0] += bits2f(p.x); s[1] += bits2f(p.y); s[2] += bits2f(p.z); s[3] += bits2f(p.w);
    }
    float4 o = {s[0], s[1], s[2], s[3]};
    *reinterpret_cast<float4*>(&XDP[i]) = o;
    int col = (int)(i & (XDP_LD - 1));
    if (col < DTR) {
        size_t row = i >> 7;
        bf16 r[4];
#pragma unroll
        for (int j = 0; j < 4; ++j) r[j] = __float2bfloat16(s[j]);
        *reinterpret_cast<ushort4*>(&XDdt[row * DTR + col]) = *reinterpret_cast<ushort4*>(r);
    }
}

// ---------------- dt GEMM fallback (vector, K=64, reads XDP fp32) ----------------
__global__ __launch_bounds__(256) void gemm_dt(const float* __restrict__ A,   // lda=128
                                               const float* __restrict__ Bw,  // 64 x 2048 f32
                                               const float* __restrict__ bias,
                                               bf16* __restrict__ Cb, int M, int N) {
    __shared__ float As[16][68];
    __shared__ float Bs[16][68];
    int tid = threadIdx.x;
    int bm = blockIdx.y * 64, bn = blockIdx.x * 64;
    int tx = tid & 15, ty = tid >> 4;
    float acc[4][4];
#pragma unroll
    for (int i = 0; i < 4; ++i)
#pragma unroll
        for (int j = 0; j < 4; ++j) acc[i][j] = 0.f;
    int arow = tid >> 2, acg = (tid & 3) * 4;
    int brow = tid >> 4, bcol = (tid & 15) * 4;
    for (int k0 = 0; k0 < DTR; k0 += 16) {
        float4 av = *reinterpret_cast<const float4*>(&A[(size_t)(bm + arow) * XDP_LD + k0 + acg]);
        As[acg + 0][arow] = av.x; As[acg + 1][arow] = av.y;
        As[acg + 2][arow] = av.z; As[acg + 3][arow] = av.w;
        float4 bv = *reinterpret_cast<const float4*>(&Bw[(size_t)(k0 + brow) * N + bn + bcol]);
        Bs[brow][bcol + 0] = bv.x; Bs[brow][bcol + 1] = bv.y;
        Bs[brow][bcol + 2] = bv.z; Bs[brow][bcol + 3] = bv.w;
        __syncthreads();
#pragma unroll
        for (int kk = 0; kk < 16; ++kk) {
            float4 a = *reinterpret_cast<const float4*>(&As[kk][ty * 4]);
            float4 b = *reinterpret_cast<const float4*>(&Bs[kk][tx * 4]);
            acc[0][0] += a.x * b.x; acc[0][1] += a.x * b.y; acc[0][2] += a.x * b.z; acc[0][3] += a.x * b.w;
            acc[1][0] += a.y * b.x; acc[1][1] += a.y * b.y; acc[1][2] += a.y * b.z; acc[1][3] += a.y * b.w;
            acc[2][0] += a.z * b.x; acc[2][1] += a.z * b.y; acc[2][2] += a.z * b.z; acc[2][3] += a.z * b.w;
            acc[3][0] += a.w * b.x; acc[3][1] += a.w * b.y; acc[3][2] += a.w * b.z; acc[3][3] += a.w * b.w;
        }
        __syncthreads();
    }
    int row0 = bm + ty * 4, col0 = bn + tx * 4;
#pragma unroll
    for (int i = 0; i < 4; ++i)
#pragma unroll
        for (int j = 0; j < 4; ++j) {
            float v = acc[i][j] + bias[col0 + j];
            float sp = (v > 20.f) ? v : log1pf(__expf(v));
            Cb[(size_t)(row0 + i) * N + col0 + j] = __float2bfloat16(sp);
        }
}

// ---------------- depthwise causal conv (fwd) + anti-causal (bwd) + SiLU ----------------
__global__ __launch_bounds__(256) void conv_kernel(const bf16* __restrict__ XZ,
                                                   const float* __restrict__ wf, const float* __restrict__ bf_,
                                                   const float* __restrict__ wb, const float* __restrict__ bb_,
                                                   bf16* __restrict__ XCF, bf16* __restrict__ XCB) {
    int idx = blockIdx.x * 256 + threadIdx.x;   // over T_TOK*DI
    int c = idx & (DI - 1);
    int g = idx >> 11;
    int l = g & (SEQ - 1);
    int b = g >> 10;
    float sf = bf_[c];
    float sb = bb_[c];
#pragma unroll
    for (int j = 0; j < 4; ++j) {
        int lf = l - 3 + j;
        if (lf >= 0) sf += wf[c * 4 + j] * b2f(XZ[((size_t)(b * SEQ + lf)) * N2 + c]);
        int lb = l + 3 - j;
        if (lb < SEQ) sb += wb[c * 4 + j] * b2f(XZ[((size_t)(b * SEQ + lb)) * N2 + c]);
    }
    XCF[idx] = __float2bfloat16(sf / (1.f + __expf(-sf)));
    XCB[idx] = __float2bfloat16(sb / (1.f + __expf(-sb)));
}

// ---------------- chunked selective scan (3 kernels, HW stream barriers) ----------------
template <bool FINAL>
__global__ __launch_bounds__(256) void scan_chunk(const bf16* __restrict__ DTF_, const bf16* __restrict__ DTB_,
                                                  const bf16* __restrict__ XCF_, const bf16* __restrict__ XCB_,
                                                  const float* __restrict__ XDP,
                                                  const float* __restrict__ Af, const float* __restrict__ Ab,
                                                  const float* __restrict__ Df, const float* __restrict__ Db,
                                                  float* __restrict__ HLOC, float* __restrict__ SUMDT,
                                                  bf16* __restrict__ YCAT) {
    int c = blockIdx.x * 256 + threadIdx.x;
    int b = blockIdx.y;
    int dir = blockIdx.z >> 4, chunk = blockIdx.z & 15;
    const bf16* DT = dir ? DTB_ : DTF_;
    const bf16* XC = dir ? XCB_ : XCF_;
    const float* Al = dir ? Ab : Af;
    float A[NST];
#pragma unroll
    for (int n = 0; n < NST; ++n) A[n] = -__expf(Al[c * NST + n]);
    size_t base = ((((size_t)dir * BATCH + b) * NCHUNK + chunk) * DI + c);
    float h[NST];
    float Dv = 0.f;
    if (FINAL) {
#pragma unroll
        for (int n = 0; n < NST; ++n) h[n] = HLOC[base * NST + n];
        Dv = (dir ? Db : Df)[c];
    } else {
#pragma unroll
        for (int n = 0; n < NST; ++n) h[n] = 0.f;
    }
    float sumdt = 0.f;
    for (int it = 0; it < CLEN; ++it) {
        int sit = chunk * CLEN + it;
        int l = dir ? (SEQ - 1 - sit) : sit;
        size_t g = (size_t)b * SEQ + l;
        float dt = b2f(DT[g * DI + c]);
        float xc = b2f(XC[g * DI + c]);
        float dtxc = dt * xc;
        const float* bs = &XDP[((size_t)dir * T_TOK + g) * XDP_LD + DTR];
        if (FINAL) {
            float y = 0.f;
#pragma unroll
            for (int n = 0; n < NST; ++n) {
                h[n] = __expf(dt * A[n]) * h[n] + dtxc * bs[n];
                y += h[n] * bs[NST + n];
            }
            YCAT[g * N2 + dir * DI + c] = __float2bfloat16(y + xc * Dv);
        } else {
            sumdt += dt;
#pragma unroll
            for (int n = 0; n < NST; ++n)
                h[n] = __expf(dt * A[n]) * h[n] + dtxc * bs[n];
        }
    }
    if (!FINAL) {
#pragma unroll
        for (int n = 0; n < NST; ++n) HLOC[base * NST + n] = h[n];
        SUMDT[base] = sumdt;
    }
}

// phase B: sequential combine over chunks; rewrites HLOC[k] with carry-in h for chunk k
__global__ __launch_bounds__(256) void scan_combine(float* __restrict__ HLOC,
                                                    const float* __restrict__ SUMDT,
                                                    const float* __restrict__ Af,
                                                    const float* __restrict__ Ab) {
    int idx = blockIdx.x * 256 + threadIdx.x;   // over 2*BATCH*DI*NST = 131072
    int n = idx & 15;
    int c = (idx >> 4) & (DI - 1);
    int b = (idx >> 15) & 1;
    int dir = idx >> 16;
    float A = -__expf((dir ? Ab : Af)[c * NST + n]);
    float h = 0.f;
    for (int k = 0; k < NCHUNK; ++k) {
        size_t base = ((((size_t)dir * BATCH + b) * NCHUNK + k) * DI + c);
        float P = __expf(A * SUMDT[base]);
        float hl = HLOC[base * NST + n];
        HLOC[base * NST + n] = h;
        h = P * h + hl;
    }
}

// ---------------- gating fallback: YM *= silu(z) ----------------
__global__ __launch_bounds__(256) void gate_kernel(bf16* __restrict__ YM, const bf16* __restrict__ XZ) {
    int idx = blockIdx.x * 256 + threadIdx.x;  // over T_TOK*DI
    int t = idx >> 11;
    int c = idx & (DI - 1);
    float z = b2f(XZ[(size_t)t * N2 + DI + c]);
    float y = b2f(YM[idx]);
    YM[idx] = __float2bfloat16(y * (z / (1.f + __expf(-z))));
}

extern "C" void kernel_launch(void* const* d_in, const int* in_sizes, int n_in,
                              void* d_out, int out_size, void* d_ws, size_t ws_size,
                              hipStream_t stream) {
    const float* x       = (const float*)d_in[0];
    const float* gamma   = (const float*)d_in[1];
    const float* beta    = (const float*)d_in[2];
    const float* in_w    = (const float*)d_in[3];
    const float* conv_w  = (const float*)d_in[4];
    const float* conv_b  = (const float*)d_in[5];
    const float* xproj_w = (const float*)d_in[6];
    const float* dt_w    = (const float*)d_in[7];
    const float* dt_b    = (const float*)d_in[8];
    const float* A_log   = (const float*)d_in[9];
    const float* D_skip  = (const float*)d_in[10];
    const float* conv_w_b  = (const float*)d_in[11];
    const float* conv_b_b  = (const float*)d_in[12];
    const float* xproj_w_b = (const float*)d_in[13];
    const float* dt_w_b    = (const float*)d_in[14];
    const float* dt_b_b    = (const float*)d_in[15];
    const float* A_log_b   = (const float*)d_in[16];
    const float* D_skip_b  = (const float*)d_in[17];
    const float* merge_w   = (const float*)d_in[18];
    const float* out_w     = (const float*)d_in[19];
    float* out = (float*)d_out;

    // ---- base workspace layout ----
    char* w = (char*)d_ws;
    size_t off = 0;
    bf16* H       = (bf16*)(w + off); off += (size_t)T_TOK * DM * 2;          //  4.19 MB
    bf16* XZ      = (bf16*)(w + off); off += (size_t)T_TOK * N2 * 2;          // 16.78 MB
    bf16* XCF     = (bf16*)(w + off); off += (size_t)T_TOK * DI * 2;          //  8.39 MB
    bf16* XCB     = (bf16*)(w + off); off += (size_t)T_TOK * DI * 2;          //  8.39 MB
    bf16* XPF     = (bf16*)(w + off); off += (size_t)XDP_LD * DI * 2;         //  0.52 MB
    bf16* XPB     = (bf16*)(w + off); off += (size_t)XDP_LD * DI * 2;         //  0.52 MB
    float* XDP    = (float*)(w + off); off += (size_t)2 * T_TOK * XDP_LD * 4; //  2.10 MB
    bf16* DTF     = (bf16*)(w + off); off += (size_t)T_TOK * DI * 2;          //  8.39 MB
    bf16* DTB     = (bf16*)(w + off); off += (size_t)T_TOK * DI * 2;          //  8.39 MB (contig after DTF)
    bf16* YCAT    = (bf16*)(w + off); off += (size_t)T_TOK * N2 * 2;          // 16.78 MB
    bf16* in_wT   = (bf16*)(w + off); off += (size_t)N2 * DM * 2;             //  8.39 MB
    bf16* out_wT  = (bf16*)(w + off); off += (size_t)DM * DI * 2;             //  4.19 MB
    bf16* merge_wT= (bf16*)(w + off); off += (size_t)DI * N2 * 2;             // 16.78 MB
    bf16* dtwT    = (bf16*)(w + off); off += (size_t)2 * DI * DTR * 2;        //  0.52 MB
    bf16* XDdt    = (bf16*)(w + off); off += (size_t)2 * T_TOK * DTR * 2;     //  0.52 MB
    // PART region: time-shared {xdbl partials | HLOC+SUMDT | merge partials | out partials}
    char* PART = w + off;
    size_t avail = (ws_size > off) ? ws_size - off : 0;

    float* HLOC  = (float*)PART;                                              // 8.39 MB
    float* SUMDT = (float*)(PART + (size_t)2 * BATCH * NCHUNK * DI * NST * 4);// +0.52 MB
    bf16* Pb     = (bf16*)PART;                                               // split-K bf16 partials
    bf16* YM     = DTF;    // alias: DTF dead after scan C

    size_t MNm = (size_t)T_TOK * DI;          // merge partial elems
    size_t MNo = (size_t)T_TOK * DM;          // out partial elems
    size_t MNx = (size_t)2 * T_TOK * XDP_LD;  // xdbl partial elems
    int s_merge = (avail >= 4 * MNm * 2) ? 4 : (avail >= 2 * MNm * 2) ? 2 : 0;
    int s_out   = (avail >= 4 * MNo * 2) ? 4 : (avail >= 2 * MNo * 2) ? 2 : 0;
    int s_xdbl  = (avail >= 16 * MNx * 2) ? 16 : (avail >= 8 * MNx * 2) ? 8 : (avail >= 4 * MNx * 2) ? 4 : 0;

    // 1. mega prep: LN + in_wT + out_wT + merge_wT + xproj/dtw
    prep_mega<<<LN_BLKS + INW_T + OUTW_T + MRGW_T + SMALL_BLK, 256, 0, stream>>>(
        x, gamma, beta, H, in_w, in_wT, out_w, out_wT, merge_w, merge_wT,
        xproj_w, xproj_w_b, XPF, XPB, dt_w, dt_w_b, dtwT);
    // 2. xz = H @ in_w  (M=2048, N=4096, K=1024) -> XZ bf16
    mfma_gemm<0><<<dim3(N2 / 128, T_TOK / 128), 256, 0, stream>>>(
        H, in_wT, in_wT, 1 << 30, XZ, nullptr, nullptr, nullptr, nullptr, nullptr, T_TOK, N2, DM);
    // 3. depthwise conv + silu, both dirs
    conv_kernel<<<(T_TOK * DI) / 256, 256, 0, stream>>>(XZ, conv_w, conv_b, conv_w_b, conv_b_b, XCF, XCB);
    // 4. x_dbl (padded): XDP = [XCF;XCB] @ xproj (M=4096, N=128, K=2048), B per dir
    if (s_xdbl) {
        mfma_gemm<3><<<dim3(1, (2 * T_TOK) / 128, s_xdbl), 256, 0, stream>>>(
            XCF, XPF, XPB, (T_TOK / 128), nullptr, nullptr, nullptr, Pb, nullptr, nullptr,
            2 * T_TOK, XDP_LD, DI);
        reduce_xdbl<<<(int)(MNx / 4 / 256), 256, 0, stream>>>(Pb, s_xdbl, MNx, XDP, XDdt);
        // 5. dt = softplus(XDdt @ dt_w + dt_b) via MFMA (M=4096 both dirs, N=2048, K=64)
        mfma_gemm<4><<<dim3(DI / 128, (2 * T_TOK) / 128), 256, 0, stream>>>(
            XDdt, dtwT, dtwT + (size_t)DI * DTR, (T_TOK / 128), DTF, nullptr, nullptr, nullptr,
            dt_b, dt_b_b, 2 * T_TOK, DI, DTR);
    } else {
        mfma_gemm<2><<<dim3(1, (2 * T_TOK) / 128), 256, 0, stream>>>(
            XCF, XPF, XPB, (T_TOK / 128), nullptr, nullptr, XDP, nullptr, nullptr, nullptr,
            2 * T_TOK, XDP_LD, DI);
        gemm_dt<<<dim3(DI / 64, T_TOK / 64), 256, 0, stream>>>(XDP, dt_w, dt_b, DTF, T_TOK, DI);
        gemm_dt<<<dim3(DI / 64, T_TOK / 64), 256, 0, stream>>>(XDP + (size_t)T_TOK * XDP_LD, dt_w_b, dt_b_b, DTB, T_TOK, DI);
    }
    // 6-8. chunked scan (3 kernels; stream boundaries are the grid barriers)
    scan_chunk<false><<<dim3(DI / 256, BATCH, 2 * NCHUNK), 256, 0, stream>>>(
        DTF, DTB, XCF, XCB, XDP, A_log, A_log_b, D_skip, D_skip_b, HLOC, SUMDT, YCAT);
    scan_combine<<<(2 * BATCH * DI * NST) / 256, 256, 0, stream>>>(HLOC, SUMDT, A_log, A_log_b);
    scan_chunk<true><<<dim3(DI / 256, BATCH, 2 * NCHUNK), 256, 0, stream>>>(
        DTF, DTB, XCF, XCB, XDP, A_log, A_log_b, D_skip, D_skip_b, HLOC, SUMDT, YCAT);
    // 9. YM = silu(z) * (YCAT @ merge_w) (M=2048, N=2048, K=4096)
    if (s_merge) {
        mfma_gemm<3><<<dim3(DI / 128, T_TOK / 128, s_merge), 256, 0, stream>>>(
            YCAT, merge_wT, merge_wT, 1 << 30, nullptr, nullptr, nullptr, Pb, nullptr, nullptr,
            T_TOK, DI, N2);
        reduce_gate<<<(int)(MNm / 4 / 256), 256, 0, stream>>>(Pb, s_merge, MNm, XZ, YM);
    } else {
        mfma_gemm<0><<<dim3(DI / 128, T_TOK / 128), 256, 0, stream>>>(
            YCAT, merge_wT, merge_wT, 1 << 30, YM, nullptr, nullptr, nullptr, nullptr, nullptr,
            T_TOK, DI, N2);
        gate_kernel<<<(T_TOK * DI) / 256, 256, 0, stream>>>(YM, XZ);
    }
    // 10. out = x + YM @ out_w (M=2048, N=1024, K=2048), f32
    if (s_out) {
        mfma_gemm<3><<<dim3(DM / 128, T_TOK / 128, s_out), 256, 0, stream>>>(
            YM, out_wT, out_wT, 1 << 30, nullptr, nullptr, nullptr, Pb, nullptr, nullptr,
            T_TOK, DM, DI);
        reduce_out<<<(int)(MNo / 4 / 256), 256, 0, stream>>>(Pb, s_out, MNo, x, out);
    } else {
        mfma_gemm<1><<<dim3(DM / 128, T_TOK / 128), 256, 0, stream>>>(
            YM, out_wT, out_wT, 1 << 30, nullptr, x, out, nullptr, nullptr, nullptr,
            T_TOK, DM, DI);
    }
}